// Round 11
// baseline (289.246 us; speedup 1.0000x reference)
//
#include <hip/hip_runtime.h>

typedef short v8s __attribute__((ext_vector_type(8)));
typedef float v4f __attribute__((ext_vector_type(4)));
typedef float f32x16 __attribute__((ext_vector_type(16)));
typedef unsigned int v2u __attribute__((ext_vector_type(2)));
typedef unsigned int v4u __attribute__((ext_vector_type(4)));
typedef unsigned short ushort_t;

#define NC 256
#define ND 128

__device__ __forceinline__ unsigned short f2bf(float f) {
  union { float f; unsigned int u; } v; v.f = f;
  unsigned int u = v.u;
  unsigned int r = (u + 0x7fffu + ((u >> 16) & 1u)) >> 16;
  return (unsigned short)r;
}

__device__ __forceinline__ unsigned int cvt_pk_bf16(float a, float b) {
  unsigned int r;
  asm("v_cvt_pk_bf16_f32 %0, %1, %2" : "=v"(r) : "v"(a), "v"(b));
  return r;
}

__device__ __forceinline__ void plane32swap(unsigned int &a, unsigned int &b) {
  asm("v_permlane32_swap_b32 %0, %1" : "+v"(a), "+v"(b));
}

__device__ __forceinline__ float bf_lo(unsigned int u) { return __uint_as_float(u << 16); }
__device__ __forceinline__ float bf_hi(unsigned int u) { return __uint_as_float(u & 0xffff0000u); }

// ---------------- prep: fragment-arranged bf16 P/G/PT, norms, gate (R6 verbatim) ------
__global__ void som_prep_kernel(const float* __restrict__ P, const float* __restrict__ G,
                                const float* __restrict__ gate_logits,
                                ushort_t* __restrict__ PbfA, ushort_t* __restrict__ GbfA,
                                ushort_t* __restrict__ PTbfA,
                                float* __restrict__ b2p, float* __restrict__ b2g,
                                float* __restrict__ gatev) {
  int c = blockIdx.x;      // 0..255
  int t = threadIdx.x;     // 0..127 (= d / k index)
  float p = P[c * ND + t];
  float g = G[c * ND + t];

  int ct = c >> 5, l31 = c & 31;
  int s = t >> 4, hia = (t >> 3) & 1, j = t & 7;
  int lane = l31 + 32 * hia;
  PbfA[((ct * 8 + s) * 64 + lane) * 8 + j] = f2bf(p);
  GbfA[((ct * 8 + s) * 64 + lane) * 8 + j] = f2bf(g);

  int dt = t >> 5, l31d = t & 31;
  int sc = c >> 4, hic = (c >> 3) & 1, jc = c & 7;
  int laned = l31d + 32 * hic;
  PTbfA[((dt * 16 + sc) * 64 + laned) * 8 + jc] = f2bf(p);

  float pp = p * p, gg = g * g;
  #pragma unroll
  for (int m = 1; m < 64; m <<= 1) { pp += __shfl_xor(pp, m); gg += __shfl_xor(gg, m); }
  __shared__ float sp[2], sg[2];
  if ((t & 63) == 0) { sp[t >> 6] = pp; sg[t >> 6] = gg; }
  __syncthreads();
  if (t == 0) {
    b2p[c] = sp[0] + sp[1];
    b2g[c] = sg[0] + sg[1];
    gatev[c] = 1.f / (1.f + expf(-gate_logits[c]));
  }
}

// ---------------- fused main kernel: R6 phases, half-reg/half-LDS u ----------------
// 1 wave = 32 rows, S^T orientation (lane = col m = l31). u for ct 0..3 kept packed in
// 32 VGPRs; ct 4..7 in 8KB/wave swizzled LDS. Blend B-frags: permlane (reg half) +
// LDS reads (LDS half). All global stores are sector-complete full-128B-line bursts.
__global__ __launch_bounds__(256, 4) void som_main_kernel(
    const float* __restrict__ x,
    const ushort_t* __restrict__ PbfA,
    const ushort_t* __restrict__ GbfA,
    const ushort_t* __restrict__ PTbfA,
    const float* __restrict__ b2p,
    const float* __restrict__ b2g,
    const float* __restrict__ gatev,
    const float* __restrict__ temp_raw,
    float* __restrict__ blended_out,
    float* __restrict__ w_out)
{
  __shared__ char smem[32768];                 // 4 waves x 8 KB, per-wave private
  const int tid  = threadIdx.x;
  const int wid  = tid >> 6;
  const int lane = tid & 63;
  const int l31  = lane & 31;
  const int hi   = lane >> 5;
  const long long R = ((long long)blockIdx.x * 4 + wid) * 32;
  char* wl = smem + wid * 8192;
  const int rsw = (l31 & 15) << 4;             // row swizzle (16B slots) for own row

  float traw = temp_raw[0];
  float sgm = 1.f / (1.f + __builtin_amdgcn_exp2f(-traw * 1.44269504f));
  float T = sgm * (1.f - 1e-3f) + 1e-3f;
  float k2 = 1.44269504f / T;                  // e = exp2(-d * k2)

  // ---- X B-fragments (col m = l31) + exact f32 row norm ----
  const float* xr = x + (R + l31) * ND + hi * 8;
  v8s xb[8];
  float a2 = 0.f;
  #pragma unroll
  for (int s = 0; s < 8; ++s) {
    v4f lo = *(const v4f*)(xr + s * 16);
    v4f h4 = *(const v4f*)(xr + s * 16 + 4);
    v4u w;
    w[0] = cvt_pk_bf16(lo[0], lo[1]);
    w[1] = cvt_pk_bf16(lo[2], lo[3]);
    w[2] = cvt_pk_bf16(h4[0], h4[1]);
    w[3] = cvt_pk_bf16(h4[2], h4[3]);
    xb[s] = __builtin_bit_cast(v8s, w);
    #pragma unroll
    for (int j = 0; j < 4; ++j) {
      a2 = fmaf(lo[j], lo[j], a2);
      a2 = fmaf(h4[j], h4[j], a2);
    }
  }
  a2 += __shfl_xor(a2, 32);                    // ||x_row||^2, row = l31

  // ---- dist loop (R6): ct 0..3 -> u0 regs; ct 4..7 -> LDS ----
  unsigned int u0[32];
  float s1 = 0.f, su = 0.f;
  const ushort_t* pb = PbfA + lane * 8;
  const ushort_t* gb = GbfA + lane * 8;
  #pragma unroll
  for (int ct = 0; ct < 8; ++ct) {
    f32x16 aP, aG;
    #pragma unroll
    for (int i = 0; i < 16; ++i) { aP[i] = 0.f; aG[i] = 0.f; }
    #pragma unroll
    for (int s = 0; s < 8; ++s) {
      v8s ap = *(const v8s*)(pb + (ct * 8 + s) * 512);
      v8s ag = *(const v8s*)(gb + (ct * 8 + s) * 512);
      aP = __builtin_amdgcn_mfma_f32_32x32x16_bf16(ap, xb[s], aP, 0, 0, 0);
      aG = __builtin_amdgcn_mfma_f32_32x32x16_bf16(ag, xb[s], aG, 0, 0, 0);
    }
    #pragma unroll
    for (int q = 0; q < 4; ++q) {
      int c0 = ct * 32 + q * 8 + hi * 4;
      v4f bp = *(const v4f*)(b2p + c0);
      v4f bg = *(const v4f*)(b2g + c0);
      v4f gt = *(const v4f*)(gatev + c0);
      float uf[4];
      #pragma unroll
      for (int j2 = 0; j2 < 4; ++j2) {
        int r = q * 4 + j2;
        float d2a = fmaf(-2.f, aP[r], a2 + bp[j2]);
        float d2b = fmaf(-2.f, aG[r], a2 + bg[j2]);
        float d = __builtin_amdgcn_sqrtf(fmaxf(d2a, 1e-12f))
                + __builtin_amdgcn_sqrtf(fmaxf(d2b, 1e-12f));
        float e = __builtin_amdgcn_exp2f(-d * k2);
        float uu = e * gt[j2];
        s1 += e; su += uu;
        uf[j2] = uu;
      }
      unsigned int pk0 = cvt_pk_bf16(uf[0], uf[1]);
      unsigned int pk1 = cvt_pk_bf16(uf[2], uf[3]);
      if (ct < 4) {
        u0[ct * 8 + 2 * q]     = pk0;
        u0[ct * 8 + 2 * q + 1] = pk1;
      } else {
        v2u pk; pk[0] = pk0; pk[1] = pk1;
        *(v2u*)(wl + l31 * 256 + (((ct - 4) * 64 + q * 16 + hi * 8) ^ rsw)) = pk;
      }
    }
  }
  s1 += __shfl_xor(s1, 32);
  su += __shfl_xor(su, 32);
  float scale = 1.f / (su + 1e-8f * (s1 + 1e-8f));   // exact algebra of double norm

  // ---- blend: s2 0..7 via permlane from u0; s2 8..15 from LDS ----
  f32x16 acc[4];
  #pragma unroll
  for (int dt = 0; dt < 4; ++dt)
    #pragma unroll
    for (int i = 0; i < 16; ++i) acc[dt][i] = 0.f;
  const ushort_t* tb = PTbfA + lane * 8;
  #pragma unroll
  for (int s2 = 0; s2 < 16; ++s2) {
    v8s bfrag;
    if (s2 < 8) {
      int ct = s2 >> 1, b = s2 & 1;
      unsigned int p0 = u0[ct * 8 + 4 * b], p1 = u0[ct * 8 + 4 * b + 1];
      unsigned int p2 = u0[ct * 8 + 4 * b + 2], p3 = u0[ct * 8 + 4 * b + 3];
      plane32swap(p0, p2);
      plane32swap(p1, p3);
      v4u bw; bw[0] = p0; bw[1] = p1; bw[2] = p2; bw[3] = p3;
      bfrag = __builtin_bit_cast(v8s, bw);
    } else {
      v4u bw = *(const v4u*)(wl + l31 * 256 + (((s2 - 8) * 32 + hi * 16) ^ rsw));
      bfrag = __builtin_bit_cast(v8s, bw);
    }
    #pragma unroll
    for (int dt = 0; dt < 4; ++dt) {
      v8s pa = *(const v8s*)(tb + (dt * 16 + s2) * 512);
      acc[dt] = __builtin_amdgcn_mfma_f32_32x32x16_bf16(pa, bfrag, acc[dt], 0, 0, 0);
    }
  }

  const int erow = lane >> 3;                  // emit helper: 8 rows/instr
  const int eseg = lane & 7;

  // ---- w emit half 1 (c 128..255) from LDS: full-128B-line bursts ----
  #pragma unroll
  for (int p = 0; p < 4; ++p) {
    int row = erow + 8 * p;
    float rsc = __shfl(scale, row);
    float* wdst = w_out + (size_t)(R + row) * NC + 128 + eseg * 4;
    #pragma unroll
    for (int ch = 0; ch < 4; ++ch) {
      v2u pk = *(const v2u*)(wl + row * 256 + ((ch * 64 + eseg * 8) ^ ((row & 15) << 4)));
      v4f wv;
      wv[0] = bf_lo(pk[0]) * rsc;
      wv[1] = bf_hi(pk[0]) * rsc;
      wv[2] = bf_lo(pk[1]) * rsc;
      wv[3] = bf_hi(pk[1]) * rsc;
      *(v4f*)(wdst + ch * 32) = wv;
    }
  }

  // ---- stage u0 -> LDS (frees regs), then w emit half 0 (c 0..127) ----
  #pragma unroll
  for (int ct = 0; ct < 4; ++ct) {
    #pragma unroll
    for (int q = 0; q < 4; ++q) {
      v2u pk; pk[0] = u0[ct * 8 + 2 * q]; pk[1] = u0[ct * 8 + 2 * q + 1];
      *(v2u*)(wl + l31 * 256 + ((ct * 64 + q * 16 + hi * 8) ^ rsw)) = pk;
    }
  }
  #pragma unroll
  for (int p = 0; p < 4; ++p) {
    int row = erow + 8 * p;
    float rsc = __shfl(scale, row);
    float* wdst = w_out + (size_t)(R + row) * NC + eseg * 4;
    #pragma unroll
    for (int ch = 0; ch < 4; ++ch) {
      v2u pk = *(const v2u*)(wl + row * 256 + ((ch * 64 + eseg * 8) ^ ((row & 15) << 4)));
      v4f wv;
      wv[0] = bf_lo(pk[0]) * rsc;
      wv[1] = bf_hi(pk[0]) * rsc;
      wv[2] = bf_lo(pk[1]) * rsc;
      wv[3] = bf_hi(pk[1]) * rsc;
      *(v4f*)(wdst + ch * 32) = wv;
    }
  }

  // ---- blended emit: two d-half passes through the 8KB tile, full lines ----
  #pragma unroll
  for (int pair = 0; pair < 2; ++pair) {
    #pragma unroll
    for (int dt2 = 0; dt2 < 2; ++dt2) {
      int dt = pair * 2 + dt2;
      #pragma unroll
      for (int q = 0; q < 4; ++q) {
        v4f ov;
        ov[0] = acc[dt][4 * q + 0] * scale;
        ov[1] = acc[dt][4 * q + 1] * scale;
        ov[2] = acc[dt][4 * q + 2] * scale;
        ov[3] = acc[dt][4 * q + 3] * scale;
        *(v4f*)(wl + l31 * 256 + ((dt2 * 128 + q * 32 + hi * 16) ^ rsw)) = ov;
      }
    }
    #pragma unroll
    for (int p = 0; p < 4; ++p) {
      int row = erow + 8 * p;
      float* bdst = blended_out + (size_t)(R + row) * ND + pair * 64 + eseg * 4;
      #pragma unroll
      for (int ch = 0; ch < 2; ++ch) {
        v4f bv = *(const v4f*)(wl + row * 256 + ((ch * 128 + eseg * 16) ^ ((row & 15) << 4)));
        *(v4f*)(bdst + ch * 32) = bv;
      }
    }
  }
}

extern "C" void kernel_launch(void* const* d_in, const int* in_sizes, int n_in,
                              void* d_out, int out_size, void* d_ws, size_t ws_size,
                              hipStream_t stream) {
  const float* x    = (const float*)d_in[0];
  const float* P    = (const float*)d_in[1];
  const float* G    = (const float*)d_in[2];
  const float* traw = (const float*)d_in[3];
  const float* gl   = (const float*)d_in[4];
  const int N = in_sizes[0] / ND;             // 262144

  char* ws = (char*)d_ws;
  ushort_t* PbfA  = (ushort_t*)(ws);
  ushort_t* GbfA  = (ushort_t*)(ws + 65536);
  ushort_t* PTbfA = (ushort_t*)(ws + 131072);
  float* b2p   = (float*)(ws + 196608);
  float* b2g   = (float*)(ws + 197632);
  float* gatev = (float*)(ws + 198656);

  float* blended = (float*)d_out;
  float* wout    = blended + (size_t)N * ND;

  som_prep_kernel<<<NC, ND, 0, stream>>>(P, G, gl, PbfA, GbfA, PTbfA, b2p, b2g, gatev);
  som_main_kernel<<<N / 128, 256, 0, stream>>>(x, PbfA, GbfA, PTbfA, b2p, b2g, gatev,
                                               traw, blended, wout);
}

// Round 12
// 130.303 us; speedup vs baseline: 2.2198x; 2.2198x over previous
//
#include <hip/hip_runtime.h>

typedef short v8s __attribute__((ext_vector_type(8)));
typedef float v4f __attribute__((ext_vector_type(4)));
typedef float f32x16 __attribute__((ext_vector_type(16)));
typedef unsigned int v2u __attribute__((ext_vector_type(2)));
typedef unsigned int v4u __attribute__((ext_vector_type(4)));
typedef unsigned short ushort_t;

#define NC 256
#define ND 128

__device__ __forceinline__ unsigned short f2bf(float f) {
  union { float f; unsigned int u; } v; v.f = f;
  unsigned int u = v.u;
  unsigned int r = (u + 0x7fffu + ((u >> 16) & 1u)) >> 16;
  return (unsigned short)r;
}

__device__ __forceinline__ unsigned int cvt_pk_bf16(float a, float b) {
  unsigned int r;
  asm("v_cvt_pk_bf16_f32 %0, %1, %2" : "=v"(r) : "v"(a), "v"(b));
  return r;
}

__device__ __forceinline__ float bf_lo(unsigned int u) { return __uint_as_float(u << 16); }
__device__ __forceinline__ float bf_hi(unsigned int u) { return __uint_as_float(u & 0xffff0000u); }

// ---------------- prep: fragment-arranged bf16 P/G/PT, norms, gate (R6 verbatim) ------
__global__ void som_prep_kernel(const float* __restrict__ P, const float* __restrict__ G,
                                const float* __restrict__ gate_logits,
                                ushort_t* __restrict__ PbfA, ushort_t* __restrict__ GbfA,
                                ushort_t* __restrict__ PTbfA,
                                float* __restrict__ b2p, float* __restrict__ b2g,
                                float* __restrict__ gatev) {
  int c = blockIdx.x;      // 0..255
  int t = threadIdx.x;     // 0..127 (= d / k index)
  float p = P[c * ND + t];
  float g = G[c * ND + t];

  int ct = c >> 5, l31 = c & 31;
  int s = t >> 4, hia = (t >> 3) & 1, j = t & 7;
  int lane = l31 + 32 * hia;
  PbfA[((ct * 8 + s) * 64 + lane) * 8 + j] = f2bf(p);
  GbfA[((ct * 8 + s) * 64 + lane) * 8 + j] = f2bf(g);

  int dt = t >> 5, l31d = t & 31;
  int sc = c >> 4, hic = (c >> 3) & 1, jc = c & 7;
  int laned = l31d + 32 * hic;
  PTbfA[((dt * 16 + sc) * 64 + laned) * 8 + jc] = f2bf(p);

  float pp = p * p, gg = g * g;
  #pragma unroll
  for (int m = 1; m < 64; m <<= 1) { pp += __shfl_xor(pp, m); gg += __shfl_xor(gg, m); }
  __shared__ float sp[2], sg[2];
  if ((t & 63) == 0) { sp[t >> 6] = pp; sg[t >> 6] = gg; }
  __syncthreads();
  if (t == 0) {
    b2p[c] = sp[0] + sp[1];
    b2g[c] = sg[0] + sg[1];
    gatev[c] = 1.f / (1.f + expf(-gate_logits[c]));
  }
}

// ---------------- fused main kernel (R6 structure + nontemporal output stores) --------
__global__ __launch_bounds__(256, 2) void som_main_kernel(
    const float* __restrict__ x,
    const ushort_t* __restrict__ PbfA,
    const ushort_t* __restrict__ GbfA,
    const ushort_t* __restrict__ PTbfA,
    const float* __restrict__ b2p,
    const float* __restrict__ b2g,
    const float* __restrict__ gatev,
    const float* __restrict__ temp_raw,
    float* __restrict__ blended_out,
    float* __restrict__ w_out)
{
  __shared__ char smem[65536];                 // 4 waves x 16 KB, per-wave private
  const int tid  = threadIdx.x;
  const int wid  = tid >> 6;
  const int lane = tid & 63;
  const int l31  = lane & 31;
  const int hi   = lane >> 5;
  const long long R = ((long long)blockIdx.x * 4 + wid) * 32;
  char* wl = smem + wid * 16384;
  const int rsw = (l31 & 7) << 4;              // row swizzle for this lane's own row

  float traw = temp_raw[0];
  float sgm = 1.f / (1.f + __builtin_amdgcn_exp2f(-traw * 1.44269504f));
  float T = sgm * (1.f - 1e-3f) + 1e-3f;
  float k2 = 1.44269504f / T;                  // e = exp2(-d * k2)

  // ---- X B-fragments (col m = l31, k = hi*8+j at tile s) + exact f32 row norm ----
  const float* xr = x + (R + l31) * ND + hi * 8;
  v8s xb[8];
  float a2 = 0.f;
  #pragma unroll
  for (int s = 0; s < 8; ++s) {
    v4f lo = *(const v4f*)(xr + s * 16);
    v4f h4 = *(const v4f*)(xr + s * 16 + 4);
    v4u w;
    w[0] = cvt_pk_bf16(lo[0], lo[1]);
    w[1] = cvt_pk_bf16(lo[2], lo[3]);
    w[2] = cvt_pk_bf16(h4[0], h4[1]);
    w[3] = cvt_pk_bf16(h4[2], h4[3]);
    xb[s] = __builtin_bit_cast(v8s, w);
    #pragma unroll
    for (int j = 0; j < 4; ++j) {
      a2 = fmaf(lo[j], lo[j], a2);
      a2 = fmaf(h4[j], h4[j], a2);
    }
  }
  a2 += __shfl_xor(a2, 32);                    // ||x_row||^2, row = l31

  // ---- dist loop: MFMA -> e*gate -> bf16 -> LDS (no register retention) ----
  float s1 = 0.f, su = 0.f;
  const ushort_t* pb = PbfA + lane * 8;
  const ushort_t* gb = GbfA + lane * 8;
  #pragma unroll
  for (int ct = 0; ct < 8; ++ct) {
    f32x16 aP, aG;
    #pragma unroll
    for (int i = 0; i < 16; ++i) { aP[i] = 0.f; aG[i] = 0.f; }
    #pragma unroll
    for (int s = 0; s < 8; ++s) {
      v8s ap = *(const v8s*)(pb + (ct * 8 + s) * 512);
      v8s ag = *(const v8s*)(gb + (ct * 8 + s) * 512);
      aP = __builtin_amdgcn_mfma_f32_32x32x16_bf16(ap, xb[s], aP, 0, 0, 0);
      aG = __builtin_amdgcn_mfma_f32_32x32x16_bf16(ag, xb[s], aG, 0, 0, 0);
    }
    #pragma unroll
    for (int q = 0; q < 4; ++q) {
      int c0 = ct * 32 + q * 8 + hi * 4;
      v4f bp = *(const v4f*)(b2p + c0);
      v4f bg = *(const v4f*)(b2g + c0);
      v4f gt = *(const v4f*)(gatev + c0);
      float uf[4];
      #pragma unroll
      for (int j2 = 0; j2 < 4; ++j2) {
        int r = q * 4 + j2;
        float d2a = fmaf(-2.f, aP[r], a2 + bp[j2]);
        float d2b = fmaf(-2.f, aG[r], a2 + bg[j2]);
        float d = __builtin_amdgcn_sqrtf(fmaxf(d2a, 1e-12f))
                + __builtin_amdgcn_sqrtf(fmaxf(d2b, 1e-12f));
        float e = __builtin_amdgcn_exp2f(-d * k2);
        float uu = e * gt[j2];
        s1 += e; su += uu;
        uf[j2] = uu;
      }
      v2u pk;
      pk[0] = cvt_pk_bf16(uf[0], uf[1]);
      pk[1] = cvt_pk_bf16(uf[2], uf[3]);
      // u[m=l31][c0..c0+3], swizzled b64 write
      *(v2u*)(wl + l31 * 512 + ((ct * 64 + q * 16 + hi * 8) ^ rsw)) = pk;
    }
  }
  s1 += __shfl_xor(s1, 32);
  su += __shfl_xor(su, 32);
  float scale = 1.f / (su + 1e-8f * (s1 + 1e-8f));   // exact algebra of double norm

  // ---- w emit: LDS-transposed, full-128B-line NT stores (8 rows x 128B / instr) ----
  #pragma unroll
  for (int p = 0; p < 4; ++p) {
    int row = (lane >> 3) + 8 * p;
    float rsc = __shfl(scale, row);
    float* wdst = w_out + (size_t)(R + row) * NC + (lane & 7) * 4;
    #pragma unroll
    for (int ch = 0; ch < 8; ++ch) {
      v2u pk = *(const v2u*)(wl + row * 512 + ((ch * 64 + (lane & 7) * 8) ^ ((row & 7) << 4)));
      v4f wv;
      wv[0] = bf_lo(pk[0]) * rsc;
      wv[1] = bf_hi(pk[0]) * rsc;
      wv[2] = bf_lo(pk[1]) * rsc;
      wv[3] = bf_hi(pk[1]) * rsc;
      __builtin_nontemporal_store(wv, (v4f*)(wdst + ch * 32));
    }
  }

  // ---- blend: blended^T = PT(32d x 16c) * U^T(16c x 32m), B-frags from LDS ----
  f32x16 acc[4];
  #pragma unroll
  for (int dt = 0; dt < 4; ++dt)
    #pragma unroll
    for (int i = 0; i < 16; ++i) acc[dt][i] = 0.f;

  const ushort_t* tb = PTbfA + lane * 8;
  #pragma unroll
  for (int s2 = 0; s2 < 16; ++s2) {
    v4u bw = *(const v4u*)(wl + l31 * 512 + ((s2 * 32 + hi * 16) ^ rsw));
    v8s bfrag = __builtin_bit_cast(v8s, bw);
    #pragma unroll
    for (int dt = 0; dt < 4; ++dt) {
      v8s pa = *(const v8s*)(tb + (dt * 16 + s2) * 512);
      acc[dt] = __builtin_amdgcn_mfma_f32_32x32x16_bf16(pa, bfrag, acc[dt], 0, 0, 0);
    }
  }

  // ---- blended emit: scale, stage f32 tile [32 m][128 d] in same LDS, NT full lines --
  #pragma unroll
  for (int dt = 0; dt < 4; ++dt) {
    #pragma unroll
    for (int q = 0; q < 4; ++q) {
      v4f ov;
      ov[0] = acc[dt][4 * q + 0] * scale;
      ov[1] = acc[dt][4 * q + 1] * scale;
      ov[2] = acc[dt][4 * q + 2] * scale;
      ov[3] = acc[dt][4 * q + 3] * scale;
      *(v4f*)(wl + l31 * 512 + ((dt * 128 + q * 32 + hi * 16) ^ rsw)) = ov;
    }
  }
  #pragma unroll
  for (int p = 0; p < 4; ++p) {
    int row = (lane >> 3) + 8 * p;
    float* bdst = blended_out + (size_t)(R + row) * ND + (lane & 7) * 4;
    #pragma unroll
    for (int ch = 0; ch < 4; ++ch) {
      v4f bv = *(const v4f*)(wl + row * 512 + ((ch * 128 + (lane & 7) * 16) ^ ((row & 7) << 4)));
      __builtin_nontemporal_store(bv, (v4f*)(bdst + ch * 32));
    }
  }
}

extern "C" void kernel_launch(void* const* d_in, const int* in_sizes, int n_in,
                              void* d_out, int out_size, void* d_ws, size_t ws_size,
                              hipStream_t stream) {
  const float* x    = (const float*)d_in[0];
  const float* P    = (const float*)d_in[1];
  const float* G    = (const float*)d_in[2];
  const float* traw = (const float*)d_in[3];
  const float* gl   = (const float*)d_in[4];
  const int N = in_sizes[0] / ND;             // 262144

  char* ws = (char*)d_ws;
  ushort_t* PbfA  = (ushort_t*)(ws);
  ushort_t* GbfA  = (ushort_t*)(ws + 65536);
  ushort_t* PTbfA = (ushort_t*)(ws + 131072);
  float* b2p   = (float*)(ws + 196608);
  float* b2g   = (float*)(ws + 197632);
  float* gatev = (float*)(ws + 198656);

  float* blended = (float*)d_out;
  float* wout    = blended + (size_t)N * ND;

  som_prep_kernel<<<NC, ND, 0, stream>>>(P, G, gl, PbfA, GbfA, PTbfA, b2p, b2g, gatev);
  som_main_kernel<<<N / 128, 256, 0, stream>>>(x, PbfA, GbfA, PTbfA, b2p, b2g, gatev,
                                               traw, blended, wout);
}